// Round 7
// baseline (122.424 us; speedup 1.0000x reference)
//
#include <hip/hip_runtime.h>
#include <math.h>

#define BATCH   256
#define IN_F    2048
#define OUT_F   256
#define NCOL    2048    /* OUT_F*KD */
#define OSTRIDE 2304    /* IN_F + OUT_F */
#define LOG2E   1.4426950408889634f

typedef float    f32x4  __attribute__((ext_vector_type(4)));
typedef short    bf16x8 __attribute__((ext_vector_type(8)));
typedef _Float16 h16x2  __attribute__((ext_vector_type(2)));
typedef __fp16   fp16x2 __attribute__((ext_vector_type(2)));
typedef unsigned short u16;
typedef unsigned int   u32;

// ws layout (rep-indexed regions, all regions of a kind hold identical data):
//   Mh[r]  f16 [256 o][256 j][8 k] : ws + r*1MiB,  r in [0,5)
//   Wt[r]  bf16 tiled              : ws + 16MiB + r*8MiB, r in [0,6)
//   Xb[r]  bf16 tiled (pre *log2e) : ws + 64MiB + r*1MiB, r in [0,6)
#define MH_STRIDE  524288u    /* u16 elements per region */
#define WT_BASE   (16u << 20)
#define WT_STRIDE  4194304u   /* u16 elements */
#define XB_BASE   (64u << 20)
#define XB_STRIDE  524288u    /* u16 elements */

__device__ __forceinline__ u16 f2bf(float f) {
    unsigned u = __builtin_bit_cast(unsigned, f);
    u += 0x7fff + ((u >> 16) & 1);              // RNE
    return (u16)(u >> 16);
}

// ---------------------------------------------------------------------------
// Prep (R6 body, rep-looped). blocks 0..127 = tconv, 128..383 = xconv+copy.
// ---------------------------------------------------------------------------
__global__ __launch_bounds__(256)
void k_prep(const float* __restrict__ X0, const float* __restrict__ T0,
            u16* __restrict__ WtB, u16* __restrict__ XbB,
            float* __restrict__ out, int reps, size_t zoff) {
    const int b = blockIdx.x, t = threadIdx.x;
    for (int rep = 0; rep < reps; ++rep) {
        const float* T = T0 + zoff * rep;       // zoff==0 at runtime, opaque
        const float* X = X0 + zoff * rep;
        u16* Wt = WtB + (size_t)rep * WT_STRIDE;
        u16* Xb = XbB + (size_t)rep * XB_STRIDE;
        if (b < 128) {
            const int np = (b & 3) * 256 + t;
            const int n  = np * 2;
            const int kg = b >> 2;
            const int nt = n >> 4, n16 = n & 15;
#pragma unroll
            for (int kc = 0; kc < 8; ++kc) {
                const int kb = kg * 64 + kc * 8;
                u16 h0[8], h1[8];
#pragma unroll
                for (int r = 0; r < 8; ++r) {
                    float2 v = *(const float2*)(T + (size_t)(kb + r) * NCOL + n);
                    h0[r] = f2bf(v.x);
                    h1[r] = f2bf(v.y);
                }
                u16* dst = Wt + ((size_t)(nt * 256 + kg * 8 + kc) * 16 + n16) * 8;
                *(float4*)dst       = *(float4*)h0;
                *(float4*)(dst + 8) = *(float4*)h1;
            }
        } else {
            const int g   = b - 128;
            const int rt  = g >> 4;
            const int kc  = (g & 15) * 16 + (t & 15);
            const int r16 = t >> 4;
            const int row = rt * 16 + r16;
            const float* src = X + (size_t)row * IN_F + kc * 8;
            float4 v0 = *(const float4*)src;
            float4 v1 = *(const float4*)(src + 4);
            u16 h[8] = {f2bf(v0.x * LOG2E), f2bf(v0.y * LOG2E),
                        f2bf(v0.z * LOG2E), f2bf(v0.w * LOG2E),
                        f2bf(v1.x * LOG2E), f2bf(v1.y * LOG2E),
                        f2bf(v1.z * LOG2E), f2bf(v1.w * LOG2E)};
            *(float4*)(Xb + ((size_t)(rt * 256 + kc) * 16 + r16) * 8) = *(float4*)h;
            float* od = out + (size_t)row * OSTRIDE + kc * 8;
            *(float4*)od       = v0;
            *(float4*)(od + 4) = v1;
        }
    }
}

// ---------------------------------------------------------------------------
// GEMM (R6 body, rep-looped; rep r reads Wt[r]/Xb[r], writes Mh[r]).
// ---------------------------------------------------------------------------
__global__ __launch_bounds__(512)
void k_gemm(const u16* __restrict__ XbB, const u16* __restrict__ WtB,
            u16* __restrict__ MhB, int reps, size_t zoff) {
    __shared__ float L[4][64][33];
    const int t = threadIdx.x, l = t & 63, w = t >> 6;
    const int bid = blockIdx.x;
    const int R  = bid >> 5;
    const int Cp = bid & 31;
    const int cw = w & 1, kcw = w >> 1;
    const int C  = Cp * 2 + cw;
    const int lo = (l >> 4) * 128 + (l & 15) * 8;
    const int lq = l >> 4, lm = l & 15;
    const int ol = t >> 6, jl = (t & 63) >> 1, k0 = (t & 1) * 4;

    for (int rep = 0; rep < reps; ++rep) {
        const u16* Xb = XbB + (size_t)rep * XB_STRIDE + zoff;
        const u16* Wt = WtB + (size_t)rep * WT_STRIDE + zoff;
        u16* Mh = MhB + (size_t)rep * MH_STRIDE;

        const u16* ap0 = Xb + (size_t)(R * 2) * 32768 + kcw * 8192 + lo;
        const u16* ap1 = ap0 + 32768;
        const u16* bp0 = Wt + (size_t)(C * 2) * 32768 + kcw * 8192 + lo;
        const u16* bp1 = bp0 + 32768;

        f32x4 c00 = {0.f,0.f,0.f,0.f}, c01 = {0.f,0.f,0.f,0.f};
        f32x4 c10 = {0.f,0.f,0.f,0.f}, c11 = {0.f,0.f,0.f,0.f};

#pragma unroll 4
        for (int s = 0; s < 16; ++s) {
            bf16x8 a0 = *(const bf16x8*)(ap0 + s * 512);
            bf16x8 a1 = *(const bf16x8*)(ap1 + s * 512);
            bf16x8 b0 = *(const bf16x8*)(bp0 + s * 512);
            bf16x8 b1 = *(const bf16x8*)(bp1 + s * 512);
            c00 = __builtin_amdgcn_mfma_f32_16x16x32_bf16(a0, b0, c00, 0, 0, 0);
            c01 = __builtin_amdgcn_mfma_f32_16x16x32_bf16(a0, b1, c01, 0, 0, 0);
            c10 = __builtin_amdgcn_mfma_f32_16x16x32_bf16(a1, b0, c10, 0, 0, 0);
            c11 = __builtin_amdgcn_mfma_f32_16x16x32_bf16(a1, b1, c11, 0, 0, 0);
        }

#define PUT(acc, qi, qj) do { \
        _Pragma("unroll") \
        for (int r = 0; r < 4; ++r) \
            L[kcw][cw * 32 + (qj) * 16 + lm][(qi) * 16 + lq * 4 + r] = acc[r]; \
    } while (0)
        PUT(c00, 0, 0); PUT(c01, 0, 1); PUT(c10, 1, 0); PUT(c11, 1, 1);
#undef PUT
        __syncthreads();

        float v[4];
#pragma unroll
        for (int i = 0; i < 4; ++i) {
            const int c = ol * 8 + k0 + i;
            v[i] = (L[0][c][jl] + L[1][c][jl]) + (L[2][c][jl] + L[3][c][jl]);
        }
        fp16x2 p0 = __builtin_amdgcn_cvt_pkrtz(v[0], v[1]);
        fp16x2 p1 = __builtin_amdgcn_cvt_pkrtz(v[2], v[3]);
        uint2 pk = {__builtin_bit_cast(u32, p0), __builtin_bit_cast(u32, p1)};
        *(uint2*)(Mh + ((size_t)(Cp * 8 + ol) * 256 + R * 32 + jl) * 8 + k0) = pk;
        __syncthreads();   // protect L before next rep's PUT
    }
}

// ---------------------------------------------------------------------------
// Pair (R6 body, rep-looped; rep r reads Mh[r]).
// ---------------------------------------------------------------------------
__global__ __launch_bounds__(512)
void k_pair(const u16* __restrict__ MhB, float* __restrict__ out,
            int reps, size_t zoff) {
    __shared__ __align__(16) uint4 Msh[BATCH];
    __shared__ float Ps[512];
    const int o = blockIdx.x, t = threadIdx.x;
    const int j = t & 255, h = t >> 8;

    for (int rep = 0; rep < reps; ++rep) {
        const u16* Mh = MhB + (size_t)rep * MH_STRIDE + zoff;
        ((uint2*)Msh)[t] = ((const uint2*)(Mh + (size_t)o * 2048))[t];
        __syncthreads();

        uint4 mm = Msh[j];
        const h16x2 m0 = __builtin_bit_cast(h16x2, mm.x);
        const h16x2 m1 = __builtin_bit_cast(h16x2, mm.y);
        const h16x2 m2 = __builtin_bit_cast(h16x2, mm.z);
        const h16x2 m3 = __builtin_bit_cast(h16x2, mm.w);

        float acc = 0.f;
        const int i0 = h * 128;
        for (int i = i0; i < i0 + 128; ++i) {
            uint4 uu = Msh[i];
            h16x2 d0 = __builtin_bit_cast(h16x2, uu.x) - m0;
            h16x2 d1 = __builtin_bit_cast(h16x2, uu.y) - m1;
            h16x2 d2 = __builtin_bit_cast(h16x2, uu.z) - m2;
            h16x2 d3 = __builtin_bit_cast(h16x2, uu.w) - m3;
            h16x2 e0 = __builtin_bit_cast(h16x2, __builtin_bit_cast(u32, d0) & 0x7fff7fffu);
            h16x2 e1 = __builtin_bit_cast(h16x2, __builtin_bit_cast(u32, d1) & 0x7fff7fffu);
            h16x2 e2 = __builtin_bit_cast(h16x2, __builtin_bit_cast(u32, d2) & 0x7fff7fffu);
            h16x2 e3 = __builtin_bit_cast(h16x2, __builtin_bit_cast(u32, d3) & 0x7fff7fffu);
            h16x2 s = (e0 + e1) + (e2 + e3);
            float norm = (float)s[0] + (float)s[1];
            acc += exp2f(-norm);
        }
        Ps[t] = acc;
        __syncthreads();
        if (t < 256)
            out[(size_t)t * OSTRIDE + IN_F + o] = Ps[t] + Ps[t + 256] - 1.0f;
        __syncthreads();   // protect Msh/Ps before next rep
    }
}

extern "C" void kernel_launch(void* const* d_in, const int* in_sizes, int n_in,
                              void* d_out, int out_size, void* d_ws, size_t ws_size,
                              hipStream_t stream) {
    const float* x = (const float*)d_in[0];   // [256, 2048]
    const float* T = (const float*)d_in[1];   // [2048][2048] flattened
    float* out = (float*)d_out;               // [256, 2304]
    char* ws = (char*)d_ws;
    u16* Mh = (u16*)ws;
    u16* Wt = (u16*)(ws + WT_BASE);
    u16* Xb = (u16*)(ws + XB_BASE);
    const size_t zoff = (size_t)(in_sizes[0] - 524288);   // == 0, opaque to compiler

    k_prep<<<384, 256, 0, stream>>>(x, T, Wt, Xb, out, 6, zoff);
    k_gemm<<<256, 512, 0, stream>>>(Xb, Wt, Mh, 5, zoff);
    k_pair<<<256, 512, 0, stream>>>(Mh, out, 4, zoff);
}

// Round 8
// 86.199 us; speedup vs baseline: 1.4202x; 1.4202x over previous
//
#include <hip/hip_runtime.h>
#include <math.h>

#define BATCH   256
#define IN_F    2048
#define OUT_F   256
#define NCOL    2048    /* OUT_F*KD */
#define OSTRIDE 2304    /* IN_F + OUT_F */
#define LOG2E   1.4426950408889634f

typedef float    f32x4  __attribute__((ext_vector_type(4)));
typedef short    bf16x8 __attribute__((ext_vector_type(8)));
typedef _Float16 h16x2  __attribute__((ext_vector_type(2)));
typedef __fp16   fp16x2 __attribute__((ext_vector_type(2)));
typedef unsigned short u16;
typedef unsigned int   u32;

// ws layout:
//   Mh[r]  f16 [256 o][256 j][8 k] : ws + r*1MiB,  r in [0,5)
//   Wt[r]  bf16 tiled              : ws + 16MiB + r*8MiB, r in [0,5)
//   Xb[r]  bf16 tiled (pre *log2e) : ws + 64MiB + r*1MiB, r in [0,5)
// (prep writes region 0 only; gemm reps cycle r%5 — regions 1..4 hold
//  stable 0xAA poison, their Mh outputs are garbage-but-deterministic and
//  never read; pair reads Mh[0] which reps 0 and 5 write with real data.)
#define MH_STRIDE  524288u
#define WT_BASE   (16u << 20)
#define WT_STRIDE  4194304u
#define XB_BASE   (64u << 20)
#define XB_STRIDE  524288u

__device__ __forceinline__ u16 f2bf(float f) {
    unsigned u = __builtin_bit_cast(unsigned, f);
    u += 0x7fff + ((u >> 16) & 1);              // RNE
    return (u16)(u >> 16);
}

__device__ __forceinline__ float exp2_fast(float x) {
#if __has_builtin(__builtin_amdgcn_exp2f)
    return __builtin_amdgcn_exp2f(x);
#else
    float r; asm("v_exp_f32 %0, %1" : "=v"(r) : "v"(x)); return r;
#endif
}

__device__ __forceinline__ float hsum_neg(h16x2 s) {
#if __has_builtin(__builtin_amdgcn_fdot2)
    const h16x2 n1 = {(_Float16)-1.0f, (_Float16)-1.0f};
    return __builtin_amdgcn_fdot2(s, n1, 0.0f, false);
#else
    return -((float)s[0] + (float)s[1]);
#endif
}

// ---------------------------------------------------------------------------
// Prep: blocks 0..127 = T transpose+convert; 128..383 = X convert + copy.
// ---------------------------------------------------------------------------
__global__ __launch_bounds__(256)
void k_prep(const float* __restrict__ X, const float* __restrict__ T,
            u16* __restrict__ Wt, u16* __restrict__ Xb,
            float* __restrict__ out) {
    const int b = blockIdx.x, t = threadIdx.x;
    if (b < 128) {
        const int np = (b & 3) * 256 + t;
        const int n  = np * 2;
        const int kg = b >> 2;
        const int nt = n >> 4, n16 = n & 15;
#pragma unroll
        for (int kc = 0; kc < 8; ++kc) {
            const int kb = kg * 64 + kc * 8;
            u16 h0[8], h1[8];
#pragma unroll
            for (int r = 0; r < 8; ++r) {
                float2 v = *(const float2*)(T + (size_t)(kb + r) * NCOL + n);
                h0[r] = f2bf(v.x);
                h1[r] = f2bf(v.y);
            }
            u16* dst = Wt + ((size_t)(nt * 256 + kg * 8 + kc) * 16 + n16) * 8;
            *(float4*)dst       = *(float4*)h0;
            *(float4*)(dst + 8) = *(float4*)h1;
        }
    } else {
        const int g   = b - 128;
        const int rt  = g >> 4;
        const int kc  = (g & 15) * 16 + (t & 15);
        const int r16 = t >> 4;
        const int row = rt * 16 + r16;
        const float* src = X + (size_t)row * IN_F + kc * 8;
        float4 v0 = *(const float4*)src;
        float4 v1 = *(const float4*)(src + 4);
        u16 h[8] = {f2bf(v0.x * LOG2E), f2bf(v0.y * LOG2E),
                    f2bf(v0.z * LOG2E), f2bf(v0.w * LOG2E),
                    f2bf(v1.x * LOG2E), f2bf(v1.y * LOG2E),
                    f2bf(v1.z * LOG2E), f2bf(v1.w * LOG2E)};
        *(float4*)(Xb + ((size_t)(rt * 256 + kc) * 16 + r16) * 8) = *(float4*)h;
        float* od = out + (size_t)row * OSTRIDE + kc * 8;
        *(float4*)od       = v0;
        *(float4*)(od + 4) = v1;
    }
}

// ---------------------------------------------------------------------------
// GEMM (R6 body, rep-looped ONLY for diagnosis; r%5 region cycling keeps
// every rep L2-cold like the single-shot run).
// ---------------------------------------------------------------------------
__global__ __launch_bounds__(512)
void k_gemm(const u16* __restrict__ XbB, const u16* __restrict__ WtB,
            u16* __restrict__ MhB, int reps, size_t zoff) {
    __shared__ float L[4][64][33];
    const int t = threadIdx.x, l = t & 63, w = t >> 6;
    const int bid = blockIdx.x;
    const int R  = bid >> 5;
    const int Cp = bid & 31;
    const int cw = w & 1, kcw = w >> 1;
    const int C  = Cp * 2 + cw;
    const int lo = (l >> 4) * 128 + (l & 15) * 8;
    const int lq = l >> 4, lm = l & 15;
    const int ol = t >> 6, jl = (t & 63) >> 1, k0 = (t & 1) * 4;

    for (int rep = 0; rep < reps; ++rep) {
        const int rg = rep % 5;
        const u16* Xb = XbB + (size_t)rg * XB_STRIDE + (size_t)rep * zoff;
        const u16* Wt = WtB + (size_t)rg * WT_STRIDE + (size_t)rep * zoff;
        u16* Mh = MhB + (size_t)rg * MH_STRIDE;

        const u16* ap0 = Xb + (size_t)(R * 2) * 32768 + kcw * 8192 + lo;
        const u16* ap1 = ap0 + 32768;
        const u16* bp0 = Wt + (size_t)(C * 2) * 32768 + kcw * 8192 + lo;
        const u16* bp1 = bp0 + 32768;

        f32x4 c00 = {0.f,0.f,0.f,0.f}, c01 = {0.f,0.f,0.f,0.f};
        f32x4 c10 = {0.f,0.f,0.f,0.f}, c11 = {0.f,0.f,0.f,0.f};

#pragma unroll 4
        for (int s = 0; s < 16; ++s) {
            bf16x8 a0 = *(const bf16x8*)(ap0 + s * 512);
            bf16x8 a1 = *(const bf16x8*)(ap1 + s * 512);
            bf16x8 b0 = *(const bf16x8*)(bp0 + s * 512);
            bf16x8 b1 = *(const bf16x8*)(bp1 + s * 512);
            c00 = __builtin_amdgcn_mfma_f32_16x16x32_bf16(a0, b0, c00, 0, 0, 0);
            c01 = __builtin_amdgcn_mfma_f32_16x16x32_bf16(a0, b1, c01, 0, 0, 0);
            c10 = __builtin_amdgcn_mfma_f32_16x16x32_bf16(a1, b0, c10, 0, 0, 0);
            c11 = __builtin_amdgcn_mfma_f32_16x16x32_bf16(a1, b1, c11, 0, 0, 0);
        }

#define PUT(acc, qi, qj) do { \
        _Pragma("unroll") \
        for (int r = 0; r < 4; ++r) \
            L[kcw][cw * 32 + (qj) * 16 + lm][(qi) * 16 + lq * 4 + r] = acc[r]; \
    } while (0)
        PUT(c00, 0, 0); PUT(c01, 0, 1); PUT(c10, 1, 0); PUT(c11, 1, 1);
#undef PUT
        __syncthreads();

        float v[4];
#pragma unroll
        for (int i = 0; i < 4; ++i) {
            const int c = ol * 8 + k0 + i;
            v[i] = (L[0][c][jl] + L[1][c][jl]) + (L[2][c][jl] + L[3][c][jl]);
        }
        fp16x2 p0 = __builtin_amdgcn_cvt_pkrtz(v[0], v[1]);
        fp16x2 p1 = __builtin_amdgcn_cvt_pkrtz(v[2], v[3]);
        uint2 pk = {__builtin_bit_cast(u32, p0), __builtin_bit_cast(u32, p1)};
        *(uint2*)(Mh + ((size_t)(Cp * 8 + ol) * 256 + R * 32 + jl) * 8 + k0) = pk;
        __syncthreads();
    }
}

// ---------------------------------------------------------------------------
// Pairwise L1-exp2, v2: 1024 threads (4 i-quarters x 256 j), fdot2 horizontal
// sum with negation folded, raw v_exp_f32. Diagonal still cancels exactly.
// ---------------------------------------------------------------------------
__global__ __launch_bounds__(1024)
void k_pair(const u16* __restrict__ Mh, float* __restrict__ out) {
    __shared__ __align__(16) uint4 Msh[BATCH];    // 4 KB
    __shared__ float Ps[1024];
    const int o = blockIdx.x, t = threadIdx.x;

    if (t < 256) Msh[t] = ((const uint4*)(Mh + (size_t)o * 2048))[t];
    __syncthreads();

    const int j = t & 255, q = t >> 8;
    uint4 mm = Msh[j];
    const h16x2 m0 = __builtin_bit_cast(h16x2, mm.x);
    const h16x2 m1 = __builtin_bit_cast(h16x2, mm.y);
    const h16x2 m2 = __builtin_bit_cast(h16x2, mm.z);
    const h16x2 m3 = __builtin_bit_cast(h16x2, mm.w);

    float acc = 0.f;
    const int i0 = q * 64;
#pragma unroll 4
    for (int i = i0; i < i0 + 64; ++i) {
        uint4 uu = Msh[i];                        // broadcast ds_read_b128
        h16x2 d0 = __builtin_bit_cast(h16x2, uu.x) - m0;
        h16x2 d1 = __builtin_bit_cast(h16x2, uu.y) - m1;
        h16x2 d2 = __builtin_bit_cast(h16x2, uu.z) - m2;
        h16x2 d3 = __builtin_bit_cast(h16x2, uu.w) - m3;
        h16x2 e0 = __builtin_bit_cast(h16x2, __builtin_bit_cast(u32, d0) & 0x7fff7fffu);
        h16x2 e1 = __builtin_bit_cast(h16x2, __builtin_bit_cast(u32, d1) & 0x7fff7fffu);
        h16x2 e2 = __builtin_bit_cast(h16x2, __builtin_bit_cast(u32, d2) & 0x7fff7fffu);
        h16x2 e3 = __builtin_bit_cast(h16x2, __builtin_bit_cast(u32, d3) & 0x7fff7fffu);
        h16x2 s = (e0 + e1) + (e2 + e3);
        acc += exp2_fast(hsum_neg(s));
    }
    Ps[t] = acc;
    __syncthreads();
    if (t < 256)
        out[(size_t)t * OSTRIDE + IN_F + o] =
            ((Ps[t] + Ps[t + 256]) + (Ps[t + 512] + Ps[t + 768])) - 1.0f;
}

extern "C" void kernel_launch(void* const* d_in, const int* in_sizes, int n_in,
                              void* d_out, int out_size, void* d_ws, size_t ws_size,
                              hipStream_t stream) {
    const float* x = (const float*)d_in[0];   // [256, 2048]
    const float* T = (const float*)d_in[1];   // [2048][2048] flattened
    float* out = (float*)d_out;               // [256, 2304]
    char* ws = (char*)d_ws;
    u16* Mh = (u16*)ws;
    u16* Wt = (u16*)(ws + WT_BASE);
    u16* Xb = (u16*)(ws + XB_BASE);
    const size_t zoff = (size_t)(in_sizes[0] - 524288);   // == 0, opaque

    k_prep<<<384, 256, 0, stream>>>(x, T, Wt, Xb, out);
    k_gemm<<<256, 512, 0, stream>>>(Xb, Wt, Mh, 10, zoff);
    k_pair<<<256, 1024, 0, stream>>>(Mh, out);
}

// Round 9
// 30.874 us; speedup vs baseline: 3.9653x; 2.7920x over previous
//
#include <hip/hip_runtime.h>
#include <math.h>

#define BATCH   256
#define IN_F    2048
#define OUT_F   256
#define NCOL    2048    /* OUT_F*KD */
#define OSTRIDE 2304    /* IN_F + OUT_F */
#define LOG2E   1.4426950408889634f

typedef float    f32x4  __attribute__((ext_vector_type(4)));
typedef short    bf16x8 __attribute__((ext_vector_type(8)));
typedef _Float16 h16x2  __attribute__((ext_vector_type(2)));
typedef __fp16   fp16x2 __attribute__((ext_vector_type(2)));
typedef unsigned short u16;
typedef unsigned int   u32;

// ws layout:
//   [0, 1MB)   Mh f16 [256 o][256 j][8 k]
//   [16,24MB)  Wt bf16 tiled [nt(128)][kc(256)][n16(16)][8]
//   [64,65MB)  Xb bf16 tiled [rt(16)][kc(256)][r16(16)][8] (pre *log2e)
#define WT_BASE   (16u << 20)
#define XB_BASE   (64u << 20)

__device__ __forceinline__ u16 f2bf(float f) {
    unsigned u = __builtin_bit_cast(unsigned, f);
    u += 0x7fff + ((u >> 16) & 1);              // RNE
    return (u16)(u >> 16);
}

__device__ __forceinline__ float exp2_fast(float x) {
#if __has_builtin(__builtin_amdgcn_exp2f)
    return __builtin_amdgcn_exp2f(x);
#else
    float r; asm("v_exp_f32 %0, %1" : "=v"(r) : "v"(x)); return r;
#endif
}

__device__ __forceinline__ float hsum_neg(h16x2 s) {
#if __has_builtin(__builtin_amdgcn_fdot2)
    const h16x2 n1 = {(_Float16)-1.0f, (_Float16)-1.0f};
    return __builtin_amdgcn_fdot2(s, n1, 0.0f, false);
#else
    return -((float)s[0] + (float)s[1]);
#endif
}

// ---------------------------------------------------------------------------
// Prep: blocks 0..127 = T transpose+convert; 128..383 = X convert + copy.
// ---------------------------------------------------------------------------
__global__ __launch_bounds__(256)
void k_prep(const float* __restrict__ X, const float* __restrict__ T,
            u16* __restrict__ Wt, u16* __restrict__ Xb,
            float* __restrict__ out) {
    const int b = blockIdx.x, t = threadIdx.x;
    if (b < 128) {
        const int np = (b & 3) * 256 + t;
        const int n  = np * 2;
        const int kg = b >> 2;
        const int nt = n >> 4, n16 = n & 15;
#pragma unroll
        for (int kc = 0; kc < 8; ++kc) {
            const int kb = kg * 64 + kc * 8;
            u16 h0[8], h1[8];
#pragma unroll
            for (int r = 0; r < 8; ++r) {
                float2 v = *(const float2*)(T + (size_t)(kb + r) * NCOL + n);
                h0[r] = f2bf(v.x);
                h1[r] = f2bf(v.y);
            }
            u16* dst = Wt + ((size_t)(nt * 256 + kg * 8 + kc) * 16 + n16) * 8;
            *(float4*)dst       = *(float4*)h0;
            *(float4*)(dst + 8) = *(float4*)h1;
        }
    } else {
        const int g   = b - 128;
        const int rt  = g >> 4;
        const int kc  = (g & 15) * 16 + (t & 15);
        const int r16 = t >> 4;
        const int row = rt * 16 + r16;
        const float* src = X + (size_t)row * IN_F + kc * 8;
        float4 v0 = *(const float4*)src;
        float4 v1 = *(const float4*)(src + 4);
        u16 h[8] = {f2bf(v0.x * LOG2E), f2bf(v0.y * LOG2E),
                    f2bf(v0.z * LOG2E), f2bf(v0.w * LOG2E),
                    f2bf(v1.x * LOG2E), f2bf(v1.y * LOG2E),
                    f2bf(v1.z * LOG2E), f2bf(v1.w * LOG2E)};
        *(float4*)(Xb + ((size_t)(rt * 256 + kc) * 16 + r16) * 8) = *(float4*)h;
        float* od = out + (size_t)row * OSTRIDE + kc * 8;
        *(float4*)od       = v0;
        *(float4*)(od + 4) = v1;
    }
}

// ---------------------------------------------------------------------------
// MFMA GEMM v3: 8-way in-block split-K for occupancy.
// 512 blocks x 8 waves; block = (R: 32-row grp 0..7, C: 32-col grp 0..63);
// bid = R*64 + C -> bid%8 = C%8 keeps same-B-panel blocks on one XCD.
// Wave w = K-chunk (256 k). 32x32 tile/wave, 2x2 fragment reuse.
// 2 blocks/CU, 4 waves/SIMD (launch_bounds cap 128 VGPR).
// C/D frag: col = l&15, row = (l>>4)*4 + reg  [m89/m91].
// ---------------------------------------------------------------------------
__global__ __launch_bounds__(512, 4)
void k_gemm(const u16* __restrict__ Xb, const u16* __restrict__ Wt,
            u16* __restrict__ Mh) {
    __shared__ float L[8][32][33];     // 33.8 KB
    const int t = threadIdx.x, l = t & 63, kcw = t >> 6;
    const int bid = blockIdx.x;
    const int R = bid >> 6;            // 0..7
    const int C = bid & 63;            // 0..63

    const int lo = (l >> 4) * 128 + (l & 15) * 8;
    const u16* ap0 = Xb + (size_t)(R * 2) * 32768 + kcw * 4096 + lo;
    const u16* ap1 = ap0 + 32768;
    const u16* bp0 = Wt + (size_t)(C * 2) * 32768 + kcw * 4096 + lo;
    const u16* bp1 = bp0 + 32768;

    f32x4 c00 = {0.f,0.f,0.f,0.f}, c01 = {0.f,0.f,0.f,0.f};
    f32x4 c10 = {0.f,0.f,0.f,0.f}, c11 = {0.f,0.f,0.f,0.f};

#pragma unroll 4
    for (int s = 0; s < 8; ++s) {
        bf16x8 a0 = *(const bf16x8*)(ap0 + s * 512);
        bf16x8 a1 = *(const bf16x8*)(ap1 + s * 512);
        bf16x8 b0 = *(const bf16x8*)(bp0 + s * 512);
        bf16x8 b1 = *(const bf16x8*)(bp1 + s * 512);
        c00 = __builtin_amdgcn_mfma_f32_16x16x32_bf16(a0, b0, c00, 0, 0, 0);
        c01 = __builtin_amdgcn_mfma_f32_16x16x32_bf16(a0, b1, c01, 0, 0, 0);
        c10 = __builtin_amdgcn_mfma_f32_16x16x32_bf16(a1, b0, c10, 0, 0, 0);
        c11 = __builtin_amdgcn_mfma_f32_16x16x32_bf16(a1, b1, c11, 0, 0, 0);
    }

    const int lq = l >> 4, lm = l & 15;
#define PUT(acc, qi, qj) do { \
        _Pragma("unroll") \
        for (int r = 0; r < 4; ++r) \
            L[kcw][(qj) * 16 + lm][(qi) * 16 + lq * 4 + r] = acc[r]; \
    } while (0)
    PUT(c00, 0, 0); PUT(c01, 0, 1); PUT(c10, 1, 0); PUT(c11, 1, 1);
#undef PUT
    __syncthreads();

    // reduce over 8 chunks + pack + coalesced 8B stores (256 lanes active)
    if (t < 256) {
        const int o2 = t >> 6;             // 0..3  (local o)
        const int jl = (t & 63) >> 1;      // 0..31 (local j)
        const int k0 = (t & 1) * 4;        // 0 or 4
        float v[4];
#pragma unroll
        for (int i = 0; i < 4; ++i) {
            const int c = o2 * 8 + k0 + i;
            float s0 = (L[0][c][jl] + L[1][c][jl]) + (L[2][c][jl] + L[3][c][jl]);
            float s1 = (L[4][c][jl] + L[5][c][jl]) + (L[6][c][jl] + L[7][c][jl]);
            v[i] = s0 + s1;
        }
        fp16x2 p0 = __builtin_amdgcn_cvt_pkrtz(v[0], v[1]);
        fp16x2 p1 = __builtin_amdgcn_cvt_pkrtz(v[2], v[3]);
        uint2 pk = {__builtin_bit_cast(u32, p0), __builtin_bit_cast(u32, p1)};
        *(uint2*)(Mh + ((size_t)(C * 4 + o2) * 256 + R * 32 + jl) * 8 + k0) = pk;
    }
}

// ---------------------------------------------------------------------------
// Pairwise L1-exp2: 1024 threads (4 i-quarters x 256 j), fdot2 h-sum with
// folded negation, raw v_exp_f32. Diagonal cancels exactly.
// ---------------------------------------------------------------------------
__global__ __launch_bounds__(1024)
void k_pair(const u16* __restrict__ Mh, float* __restrict__ out) {
    __shared__ __align__(16) uint4 Msh[BATCH];    // 4 KB
    __shared__ float Ps[1024];
    const int o = blockIdx.x, t = threadIdx.x;

    if (t < 256) Msh[t] = ((const uint4*)(Mh + (size_t)o * 2048))[t];
    __syncthreads();

    const int j = t & 255, q = t >> 8;
    uint4 mm = Msh[j];
    const h16x2 m0 = __builtin_bit_cast(h16x2, mm.x);
    const h16x2 m1 = __builtin_bit_cast(h16x2, mm.y);
    const h16x2 m2 = __builtin_bit_cast(h16x2, mm.z);
    const h16x2 m3 = __builtin_bit_cast(h16x2, mm.w);

    float acc = 0.f;
    const int i0 = q * 64;
#pragma unroll 4
    for (int i = i0; i < i0 + 64; ++i) {
        uint4 uu = Msh[i];                        // broadcast ds_read_b128
        h16x2 d0 = __builtin_bit_cast(h16x2, uu.x) - m0;
        h16x2 d1 = __builtin_bit_cast(h16x2, uu.y) - m1;
        h16x2 d2 = __builtin_bit_cast(h16x2, uu.z) - m2;
        h16x2 d3 = __builtin_bit_cast(h16x2, uu.w) - m3;
        h16x2 e0 = __builtin_bit_cast(h16x2, __builtin_bit_cast(u32, d0) & 0x7fff7fffu);
        h16x2 e1 = __builtin_bit_cast(h16x2, __builtin_bit_cast(u32, d1) & 0x7fff7fffu);
        h16x2 e2 = __builtin_bit_cast(h16x2, __builtin_bit_cast(u32, d2) & 0x7fff7fffu);
        h16x2 e3 = __builtin_bit_cast(h16x2, __builtin_bit_cast(u32, d3) & 0x7fff7fffu);
        h16x2 s = (e0 + e1) + (e2 + e3);
        acc += exp2_fast(hsum_neg(s));
    }
    Ps[t] = acc;
    __syncthreads();
    if (t < 256)
        out[(size_t)t * OSTRIDE + IN_F + o] =
            ((Ps[t] + Ps[t + 256]) + (Ps[t + 512] + Ps[t + 768])) - 1.0f;
}

extern "C" void kernel_launch(void* const* d_in, const int* in_sizes, int n_in,
                              void* d_out, int out_size, void* d_ws, size_t ws_size,
                              hipStream_t stream) {
    const float* x = (const float*)d_in[0];   // [256, 2048]
    const float* T = (const float*)d_in[1];   // [2048][2048] flattened
    float* out = (float*)d_out;               // [256, 2304]
    char* ws = (char*)d_ws;
    u16* Mh = (u16*)ws;
    u16* Wt = (u16*)(ws + WT_BASE);
    u16* Xb = (u16*)(ws + XB_BASE);

    k_prep<<<384, 256, 0, stream>>>(x, T, Wt, Xb, out);
    k_gemm<<<512, 512, 0, stream>>>(Xb, Wt, Mh);
    k_pair<<<256, 1024, 0, stream>>>(Mh, out);
}